// Round 12
// baseline (267.870 us; speedup 1.0000x reference)
//
#include <hip/hip_runtime.h>
#include <math.h>

typedef __bf16 bf16x8 __attribute__((ext_vector_type(8)));
typedef __bf16 bf16x4 __attribute__((ext_vector_type(4)));
typedef float  f32x4  __attribute__((ext_vector_type(4)));

#define QL    32
#define DL    256
#define DIM   256
#define NK    21
#define KSOFT 20
#define STR   264                 // (fallback kernel only)
#define L2E   1.4426950408889634f

#if __has_builtin(__builtin_amdgcn_exp2f)
#define EXP2F(x) __builtin_amdgcn_exp2f(x)
#else
#define EXP2F(x) exp2f(x)
#endif

// ---------- Phase 1: stream-normalize emb -> bf16 table in ws (2 rows/wave) --
__global__ __launch_bounds__(256)
void knrm_prep(const float* __restrict__ emb, __bf16* __restrict__ tab, int V)
{
    const int wave = threadIdx.x >> 6;
    const int lane = threadIdx.x & 63;
    const int row0 = (blockIdx.x * 4 + wave) * 2;
    if (row0 >= V) return;                     // V even -> row0+1 also valid

    float4 a = reinterpret_cast<const float4*>(emb + (size_t)row0 * DIM)[lane];
    float4 c = reinterpret_cast<const float4*>(emb + (size_t)(row0 + 1) * DIM)[lane];
    float sa = a.x*a.x + a.y*a.y + a.z*a.z + a.w*a.w;
    float sc = c.x*c.x + c.y*c.y + c.z*c.z + c.w*c.w;
    #pragma unroll
    for (int m = 32; m; m >>= 1) { sa += __shfl_xor(sa, m); sc += __shfl_xor(sc, m); }
    float ia = rsqrtf(fmaxf(sa, 1e-16f));      // ||row|| ~16, ref eps never binds
    float ic = rsqrtf(fmaxf(sc, 1e-16f));
    bf16x4 oa, oc;
    oa[0] = (__bf16)(a.x * ia); oa[1] = (__bf16)(a.y * ia);
    oa[2] = (__bf16)(a.z * ia); oa[3] = (__bf16)(a.w * ia);
    oc[0] = (__bf16)(c.x * ic); oc[1] = (__bf16)(c.y * ic);
    oc[2] = (__bf16)(c.z * ic); oc[3] = (__bf16)(c.w * ic);
    __builtin_nontemporal_store(oa,
        reinterpret_cast<bf16x4*>(tab + (size_t)row0 * DIM + lane * 4));
    __builtin_nontemporal_store(oc,
        reinterpret_cast<bf16x4*>(tab + (size_t)(row0 + 1) * DIM + lane * 4));
}

// ---------- Phase 2: qh-split barrier-free fragment pipeline ------------------
// grid (B, pair, qh): block evaluates 16 q-rows x 256 docs. Wave w = dh owns
// docs s*64 + dh*16 + (0..15) per superstep s=0..3. qf pinned (32 VGPR),
// af single-buffered (loads(s) overwrite af dead after MFMA(s-1), eval(s-1)
// runs meanwhile). acc[21]/lane; in-block log1p; 21-float km-partial out.
__global__ __launch_bounds__(256, 4)
void knrm_main9(const int* __restrict__ q1t, const int* __restrict__ d1t,
                const int* __restrict__ q2t, const int* __restrict__ d2t,
                const __bf16* __restrict__ tab,
                float* __restrict__ gKm, int B)
{
    const int b    = blockIdx.x;
    const int pair = blockIdx.y;
    const int qh   = blockIdx.z;    // which q-half this block evaluates
    const int tid  = threadIdx.x;
    const int dh   = tid >> 6;      // wave = doc slice within superstep
    const int lane = tid & 63;
    const int g    = lane >> 4;     // k-group for A/B; C row group
    const int cl   = lane & 15;     // A/B row; C col (= local q-row)

    const int* qtok = pair ? q2t : q1t;
    const int* dtok = pair ? d2t : d1t;

    __shared__ int   dtok_s[DL];
    __shared__ float Sqk[16 * NK];  // 336 floats — MUST use strided init (R11 bug)
    __shared__ float pkm[NK];

    dtok_s[tid] = dtok[b * DL + tid];
    for (int e = tid; e < 16 * NK; e += 256) Sqk[e] = 0.0f;
    __syncthreads();

    // ---- this lane's q-row: pinned B-fragments (32 VGPR)
    const int qtk1 = qtok[b * QL + qh * 16 + cl];
    bf16x8 qf[8];
    {
        const __bf16* pq = tab + (size_t)qtk1 * DIM + g * 8;
        #pragma unroll
        for (int ks = 0; ks < 8; ++ks)
            qf[ks] = *reinterpret_cast<const bf16x8*>(pq + ks * 32);
    }

    float acc[NK];
    #pragma unroll
    for (int k = 0; k < NK; ++k) acc[k] = 0.0f;

    // ---- superstep 0: load A-frags (doc row dh*16+cl), MFMA
    bf16x8 af[8];
    {
        const __bf16* pa = tab + (size_t)dtok_s[dh * 16 + cl] * DIM + g * 8;
        #pragma unroll
        for (int ks = 0; ks < 8; ++ks)
            af[ks] = *reinterpret_cast<const bf16x8*>(pa + ks * 32);
    }
    f32x4 cf = {0.0f, 0.0f, 0.0f, 0.0f};
    #pragma unroll
    for (int ks = 0; ks < 8; ++ks)
        cf = __builtin_amdgcn_mfma_f32_16x16x32_bf16(af[ks], qf[ks], cf, 0, 0, 0);

    // ---- supersteps 1..3: loads(s) -> eval(s-1) -> MFMA(s)
    #pragma unroll
    for (int s = 1; s < 4; ++s) {
        const __bf16* pa = tab + (size_t)dtok_s[s * 64 + dh * 16 + cl] * DIM + g * 8;
        #pragma unroll
        for (int ks = 0; ks < 8; ++ks)
            af[ks] = *reinterpret_cast<const bf16x8*>(pa + ks * 32);

        int dbase = (s - 1) * 64 + dh * 16 + g * 4;
        #pragma unroll
        for (int i = 0; i < 4; ++i) {
            int   dtk = dtok_s[dbase + i];
            float mm  = cf[i];
            float mm2 = mm * mm;
            #pragma unroll
            for (int k = 0; k < KSOFT; ++k) {
                float mu = -0.95f + 0.1f * (float)k;          // compile-time
                float a1 = 100.0f * L2E * mu;
                float a0 = -50.0f * L2E * mu * mu;
                acc[k] += EXP2F(fmaf(a1, mm, fmaf(-50.0f * L2E, mm2, a0)));
            }
            acc[KSOFT] += (dtk == qtk1) ? 1.0f : 0.0f;   // exact kernel
        }

        cf = {0.0f, 0.0f, 0.0f, 0.0f};
        #pragma unroll
        for (int ks = 0; ks < 8; ++ks)
            cf = __builtin_amdgcn_mfma_f32_16x16x32_bf16(af[ks], qf[ks], cf, 0, 0, 0);
    }

    // ---- eval superstep 3
    {
        int dbase = 3 * 64 + dh * 16 + g * 4;
        #pragma unroll
        for (int i = 0; i < 4; ++i) {
            int   dtk = dtok_s[dbase + i];
            float mm  = cf[i];
            float mm2 = mm * mm;
            #pragma unroll
            for (int k = 0; k < KSOFT; ++k) {
                float mu = -0.95f + 0.1f * (float)k;
                float a1 = 100.0f * L2E * mu;
                float a0 = -50.0f * L2E * mu * mu;
                acc[k] += EXP2F(fmaf(a1, mm, fmaf(-50.0f * L2E, mm2, a0)));
            }
            acc[KSOFT] += (dtk == qtk1) ? 1.0f : 0.0f;
        }
    }

    // ---- flush: 16 lanes (4 g x 4 dh-waves) contribute per local q-row
    #pragma unroll
    for (int k = 0; k < NK; ++k)
        atomicAdd(&Sqk[cl * NK + k], acc[k]);
    __syncthreads();

    // ---- partial km[k] = sum over this block's 16 q-rows of log1p(S)
    if (tid < NK) {
        float s = 0.0f;
        #pragma unroll
        for (int q = 0; q < 16; ++q)
            s += log1pf(Sqk[q * NK + tid]);
        pkm[tid] = s;
    }
    __syncthreads();
    if (tid < NK)
        gKm[(((size_t)pair * B + b) * 2 + qh) * NK + tid] = pkm[tid];
}

// ---------- Phase 3: merge qh-partials, MLP, sigmoid. One block per b --------
__global__ __launch_bounds__(64)
void knrm_final3(const float* __restrict__ gKm,
                 const float* __restrict__ W0, const float* __restrict__ b0,
                 const float* __restrict__ W1, const float* __restrict__ b1,
                 const float* __restrict__ W2, const float* __restrict__ b2,
                 float* __restrict__ out, int B)
{
    const int b   = blockIdx.x;
    const int tid = threadIdx.x;

    __shared__ float km[2 * NK];
    __shared__ float h0[2][10];
    __shared__ float h1[2][5];
    __shared__ float lgt[2];

    if (tid < 2 * NK) {
        int pair = tid / NK, k = tid % NK;
        const float* p = gKm + (((size_t)pair * B + b) * 2) * NK;
        km[tid] = p[k] + p[NK + k];
    }
    __syncthreads();
    if (tid < 20) {
        int pair = tid / 10, j = tid % 10;
        float h = b0[j];
        #pragma unroll
        for (int k = 0; k < NK; ++k) h = fmaf(km[pair*NK + k], W0[j*NK + k], h);
        h0[pair][j] = fmaxf(h, 0.0f);
    }
    __syncthreads();
    if (tid < 10) {
        int pair = tid / 5, j = tid % 5;
        float h = b1[j];
        #pragma unroll
        for (int i = 0; i < 10; ++i) h = fmaf(h0[pair][i], W1[j*10 + i], h);
        h1[pair][j] = fmaxf(h, 0.0f);
    }
    __syncthreads();
    if (tid < 2) {
        float l = b2[0];
        #pragma unroll
        for (int j = 0; j < 5; ++j) l = fmaf(h1[tid][j], W2[j], l);
        lgt[tid] = l;
    }
    __syncthreads();
    if (tid == 0) {
        float z = lgt[0] - lgt[1];
        out[b] = 1.0f / (1.0f + expf(-z));
    }
}

// ---------- Fallback (monolithic): ws can't hold the bf16 table ---------------
__global__ __launch_bounds__(256, 2)
void knrm_mono(const int* __restrict__ q1t, const int* __restrict__ d1t,
               const int* __restrict__ q2t, const int* __restrict__ d2t,
               const float* __restrict__ emb,
               const float* __restrict__ W0, const float* __restrict__ b0,
               const float* __restrict__ W1, const float* __restrict__ b1,
               const float* __restrict__ W2, const float* __restrict__ b2,
               float* __restrict__ out)
{
    const int b    = blockIdx.x;
    const int tid  = threadIdx.x;
    const int wave = tid >> 6;
    const int lane = tid & 63;
    const int qt   = wave >> 1;
    const int dt   = wave & 1;
    const int g    = lane >> 4;
    const int cl   = lane & 15;

    __shared__ __align__(16) __bf16 qbuf[QL * STR];
    __shared__ __align__(16) __bf16 dbuf[32 * STR];
    __shared__ float Sqk[QL * NK];
    __shared__ int   dtok_s[DL];
    __shared__ int   qtok_s[QL];
    __shared__ float km[NK];
    __shared__ float h0[10];
    __shared__ float h1[5];
    __shared__ float logit[2];

    for (int pair = 0; pair < 2; ++pair) {
        const int* qtok = pair ? q2t : q1t;
        const int* dtok = pair ? d2t : d1t;

        if (tid < QL) qtok_s[tid] = qtok[b * QL + tid];
        dtok_s[tid] = dtok[b * DL + tid];
        for (int e = tid; e < QL * NK; e += 256) Sqk[e] = 0.0f;
        if (tid < NK) km[tid] = 0.0f;
        __syncthreads();

        #pragma unroll
        for (int i = 0; i < 8; ++i) {
            int row = wave * 8 + i;
            int tok = qtok_s[row];
            float4 v = reinterpret_cast<const float4*>(emb + (size_t)tok * DIM)[lane];
            float s = v.x*v.x + v.y*v.y + v.z*v.z + v.w*v.w;
            #pragma unroll
            for (int m = 32; m; m >>= 1) s += __shfl_xor(s, m);
            float inv = rsqrtf(fmaxf(s, 1e-16f));
            bf16x4 o;
            o[0] = (__bf16)(v.x * inv); o[1] = (__bf16)(v.y * inv);
            o[2] = (__bf16)(v.z * inv); o[3] = (__bf16)(v.w * inv);
            *reinterpret_cast<bf16x4*>(&qbuf[row * STR + lane * 4]) = o;
        }

        int qtk[4];
        #pragma unroll
        for (int i = 0; i < 4; ++i) qtk[i] = qtok_s[qt * 16 + g * 4 + i];

        float acc[4 * NK];
        #pragma unroll
        for (int e = 0; e < 4 * NK; ++e) acc[e] = 0.0f;

        for (int tile = 0; tile < 8; ++tile) {
            #pragma unroll
            for (int i = 0; i < 8; ++i) {
                int r = wave * 8 + i;
                int tok = dtok_s[tile * 32 + r];
                float4 v = reinterpret_cast<const float4*>(emb + (size_t)tok * DIM)[lane];
                float s = v.x*v.x + v.y*v.y + v.z*v.z + v.w*v.w;
                #pragma unroll
                for (int m = 32; m; m >>= 1) s += __shfl_xor(s, m);
                float inv = rsqrtf(fmaxf(s, 1e-16f));
                bf16x4 o;
                o[0] = (__bf16)(v.x * inv); o[1] = (__bf16)(v.y * inv);
                o[2] = (__bf16)(v.z * inv); o[3] = (__bf16)(v.w * inv);
                *reinterpret_cast<bf16x4*>(&dbuf[r * STR + lane * 4]) = o;
            }
            __syncthreads();

            f32x4 cf = {0.0f, 0.0f, 0.0f, 0.0f};
            #pragma unroll
            for (int ks = 0; ks < 8; ++ks) {
                bf16x8 af  = *reinterpret_cast<const bf16x8*>(&qbuf[(qt*16 + cl)*STR + ks*32 + g*8]);
                bf16x8 bfr = *reinterpret_cast<const bf16x8*>(&dbuf[(dt*16 + cl)*STR + ks*32 + g*8]);
                cf = __builtin_amdgcn_mfma_f32_16x16x32_bf16(af, bfr, cf, 0, 0, 0);
            }

            int dtk = dtok_s[tile*32 + dt*16 + cl];
            #pragma unroll
            for (int i = 0; i < 4; ++i) {
                float mm  = cf[i];
                float mm2 = mm * mm;
                #pragma unroll
                for (int k = 0; k < KSOFT; ++k) {
                    float mu = -0.95f + 0.1f * (float)k;
                    float a1 = 100.0f * L2E * mu;
                    float a0 = -50.0f * L2E * mu * mu;
                    float arg = fmaf(a1, mm, fmaf(-50.0f * L2E, mm2, a0));
                    acc[i*NK + k] += EXP2F(arg);
                }
                acc[i*NK + KSOFT] += (dtk == qtk[i]) ? 1.0f : 0.0f;
            }
            __syncthreads();
        }

        #pragma unroll
        for (int i = 0; i < 4; ++i) {
            int row = qt*16 + g*4 + i;
            #pragma unroll
            for (int k = 0; k < NK; ++k)
                atomicAdd(&Sqk[row*NK + k], acc[i*NK + k]);
        }
        __syncthreads();

        for (int e = tid; e < QL * NK; e += 256)
            atomicAdd(&km[e % NK], log1pf(Sqk[e]));
        __syncthreads();

        if (tid < 10) {
            float h = b0[tid];
            #pragma unroll
            for (int k = 0; k < NK; ++k) h = fmaf(km[k], W0[tid*NK + k], h);
            h0[tid] = fmaxf(h, 0.0f);
        }
        __syncthreads();
        if (tid < 5) {
            float h = b1[tid];
            #pragma unroll
            for (int j = 0; j < 10; ++j) h = fmaf(h0[j], W1[tid*10 + j], h);
            h1[tid] = fmaxf(h, 0.0f);
        }
        __syncthreads();
        if (tid == 0) {
            float l = b2[0];
            #pragma unroll
            for (int j = 0; j < 5; ++j) l = fmaf(h1[j], W2[j], l);
            logit[pair] = l;
        }
        __syncthreads();
    }

    if (tid == 0) {
        float z = logit[0] - logit[1];
        out[b] = 1.0f / (1.0f + expf(-z));
    }
}

extern "C" void kernel_launch(void* const* d_in, const int* in_sizes, int n_in,
                              void* d_out, int out_size, void* d_ws, size_t ws_size,
                              hipStream_t stream) {
    const int*   q1  = (const int*)d_in[0];
    const int*   d1  = (const int*)d_in[1];
    const int*   q2  = (const int*)d_in[2];
    const int*   d2  = (const int*)d_in[3];
    const float* emb = (const float*)d_in[4];
    const float* W0  = (const float*)d_in[5];
    const float* b0  = (const float*)d_in[6];
    const float* W1  = (const float*)d_in[7];
    const float* b1  = (const float*)d_in[8];
    const float* W2  = (const float*)d_in[9];
    const float* b2  = (const float*)d_in[10];
    float* out = (float*)d_out;

    const int B = in_sizes[0] / QL;       // 512
    const int V = in_sizes[4] / DIM;      // 100000

    size_t tab_bytes = (size_t)V * DIM * sizeof(__bf16);
    size_t tab_al    = (tab_bytes + 255) & ~(size_t)255;
    size_t km_bytes  = (size_t)2 * B * 2 * NK * sizeof(float);   // 172 KB
    size_t need      = tab_al + km_bytes;

    if (ws_size >= need) {
        __bf16* tab = (__bf16*)d_ws;
        float*  gKm = (float*)((char*)d_ws + tab_al);

        knrm_prep<<<(V/2 + 3) / 4, 256, 0, stream>>>(emb, tab, V);
        dim3 grid(B, 2, 2);
        knrm_main9<<<grid, 256, 0, stream>>>(q1, d1, q2, d2, tab, gKm, B);
        knrm_final3<<<B, 64, 0, stream>>>(gKm, W0, b0, W1, b1, W2, b2, out, B);
    } else {
        knrm_mono<<<B, 256, 0, stream>>>(q1, d1, q2, d2, emb,
                                         W0, b0, W1, b1, W2, b2, out);
    }
}